// Round 11
// baseline (5441.741 us; speedup 1.0000x reference)
//
#include <hip/hip_runtime.h>
#include <math.h>

#define NPTS 8192
#define BATCH 2
#define MCENT 4096
#define FD 64
#define SD 5
#define AD 256

typedef float f32x2 __attribute__((ext_vector_type(2)));

// ----------------------------- FPS ---------------------------------
// One block per batch, 1024 threads, 8 points/thread, coords in VGPRs.
// r7: DPP wave reduce + u64 LDS atomicMax cross-wave (+27%).
// r9: FP contraction in this kernel (v_pk_fma emission) (+11%).
// r10 instruction diet (model: 1 VALU inst/iter = 13.6us of fps):
//  * pass B min/max as v_pk_min/max_f32 (packed, -7 insts)
//  * index-min DPP chain dropped: lanes with bv==wm atomic their own
//    packed key (value<<32 | ~idx, sign-flipped) — atomic resolves all
//    ties to lowest idx, same semantics (-11 insts)
//  * mask update only in the owner thread's wave (s_cbranch_execz skips
//    15/16 waves) (-11 effective insts)
#define FPS_T 1024
#define FPS_PAIRS 4

template<int CTRL>
__device__ __forceinline__ float dpp_max_f(float x) {
    const int o = __builtin_amdgcn_update_dpp(
        (int)0xff800000, __float_as_int(x), CTRL, 0xf, 0xf, false); // old = -inf
    return fmaxf(x, __int_as_float(o));
}

__global__ __launch_bounds__(FPS_T) __attribute__((amdgpu_waves_per_eu(4, 4)))
void fps_kernel(const float* __restrict__ spatial, int* __restrict__ idxs)
{
#pragma clang fp contract(fast)
    const int b = blockIdx.x;
    const int tid = threadIdx.x;
    const float* sp = spatial + (size_t)b * NPTS * SD;
    int* out = idxs + (size_t)b * MCENT;

    __shared__ float cs0[NPTS];              // pivot-broadcast copies (32KB x4)
    __shared__ float cs1[NPTS];
    __shared__ float cs2[NPTS];
    __shared__ float cs3[NPTS];
    __shared__ unsigned long long gk[2];     // parity-double-buffered winner key

    for (int e = tid; e < NPTS; e += FPS_T) {
        cs0[e] = sp[(size_t)e * SD + 0];
        cs1[e] = sp[(size_t)e * SD + 1];
        cs2[e] = sp[(size_t)e * SD + 2];
        cs3[e] = sp[(size_t)e * SD + 3];
    }
    if (tid == 0) { gk[0] = 0ull; gk[1] = 0ull; }

    // per-thread coords fully in registers
    f32x2 P0[FPS_PAIRS], P1[FPS_PAIRS], P2[FPS_PAIRS], P3[FPS_PAIRS], P4[FPS_PAIRS];
    f32x2 d2[FPS_PAIRS];
#pragma unroll
    for (int q = 0; q < FPS_PAIRS; ++q) {
        const int p0 = tid + ((2 * q) << 10);
        const int p1 = p0 + 1024;
        P0[q].x = sp[(size_t)p0 * SD + 0]; P0[q].y = sp[(size_t)p1 * SD + 0];
        P1[q].x = sp[(size_t)p0 * SD + 1]; P1[q].y = sp[(size_t)p1 * SD + 1];
        P2[q].x = sp[(size_t)p0 * SD + 2]; P2[q].y = sp[(size_t)p1 * SD + 2];
        P3[q].x = sp[(size_t)p0 * SD + 3]; P3[q].y = sp[(size_t)p1 * SD + 3];
        P4[q].x = sp[(size_t)p0 * SD + 4]; P4[q].y = sp[(size_t)p1 * SD + 4];
        d2[q].x = INFINITY; d2[q].y = INFINITY;
    }
    // pin coords (52 VGPR — fits budget, no spill/remat)
#pragma unroll
    for (int q = 0; q < FPS_PAIRS; ++q) {
        asm volatile("" : "+v"(P0[q]));
        asm volatile("" : "+v"(P1[q]));
        asm volatile("" : "+v"(P2[q]));
        asm volatile("" : "+v"(P3[q]));
        asm volatile("" : "+v"(P4[q]));
    }

    if (tid == 0) { d2[0].x = -INFINITY; out[0] = 0; }   // point 0 pre-selected

    float l0 = sp[0], l1 = sp[1], l2 = sp[2], l3 = sp[3], l4 = sp[4];
    __syncthreads();

    for (int i = 1; i < MCENT; ++i) {
        const int par = i & 1;
        const f32x2 L0 = {l0, l0}, L1 = {l1, l1}, L2 = {l2, l2},
                    L3 = {l3, l3}, L4 = {l4, l4};

        // pass A: dims 0..3 (l4's load latency hides under this)
        f32x2 s03[FPS_PAIRS];
#pragma unroll
        for (int q = 0; q < FPS_PAIRS; ++q) {
            f32x2 dx = P0[q] - L0; f32x2 s = dx * dx;
            f32x2 dy = P1[q] - L1; s = s + dy * dy;
            f32x2 dz = P2[q] - L2; s = s + dz * dz;
            f32x2 dw = P3[q] - L3; s = s + dw * dw;
            s03[q] = s;
        }
        // pass B: + dim4, packed min-update + packed running max
        f32x2 mx = {-INFINITY, -INFINITY};
#pragma unroll
        for (int q = 0; q < FPS_PAIRS; ++q) {
            f32x2 du = P4[q] - L4;
            f32x2 s = s03[q] + du * du;
            const f32x2 nd = __builtin_elementwise_min(d2[q], s); // -inf absorbing
            d2[q] = nd;
            mx = __builtin_elementwise_max(mx, nd);
        }
        const float bv = fmaxf(mx.x, mx.y);
        // per-thread lowest index achieving bv (descending scan, independent
        // of the DPP chain below -> overlaps in issue)
        int bi = 0x7fffffff;
#pragma unroll
        for (int q = FPS_PAIRS - 1; q >= 0; --q) {
            const int p0 = tid + ((2 * q) << 10);
            if (d2[q].y == bv) bi = p0 + 1024;
            if (d2[q].x == bv) bi = p0;
        }

        // wave-level value max via DPP (result lands in lane 63)
        float m = bv;
        m = dpp_max_f<0x111>(m);   // row_shr:1
        m = dpp_max_f<0x112>(m);   // row_shr:2
        m = dpp_max_f<0x114>(m);   // row_shr:4
        m = dpp_max_f<0x118>(m);   // row_shr:8
        m = dpp_max_f<0x142>(m);   // row_bcast:15
        m = dpp_max_f<0x143>(m);   // row_bcast:31
        const float wm = __int_as_float(
            __builtin_amdgcn_readlane(__float_as_int(m), 63));

        // every lane holding the wave max atomics its own key; the u64
        // atomicMax resolves value (hi) then lowest idx (~idx in lo) across
        // lanes AND waves — numpy argmax tie semantics
        if (bv == wm) {
            unsigned long long key =
                (((unsigned long long)(unsigned)__float_as_int(bv)) << 32)
                | (unsigned)(~bi);
            key ^= 0x8000000000000000ull;        // signed order -> unsigned max
            atomicMax(&gk[par], key);
        }
        if (tid == 0) gk[par ^ 1] = 0ull;        // reset other slot pre-barrier
        __syncthreads();

        const unsigned long long k = gk[par];
        const int gidx = ~((int)(unsigned)k);    // low word = ~idx
        // pivot loads first: global c4 (L2, hidden under pass A),
        // then LDS c0..c3 broadcast
        const int su = __builtin_amdgcn_readfirstlane(gidx);
        l4 = sp[(size_t)su * SD + 4];
        l0 = cs0[su]; l1 = cs1[su]; l2 = cs2[su]; l3 = cs3[su];
        if (tid == 0) out[i] = gidx;
        // mask the selected point — only its owner thread (1 of 1024) does
        // the 8-slot chain; waves with exec==0 branch over the body
        if (((gidx ^ tid) & 1023) == 0) {
            const int s = gidx >> 10;            // slot 0..7 (static chain)
            if (s == 0) d2[0].x = -INFINITY;
            if (s == 1) d2[0].y = -INFINITY;
            if (s == 2) d2[1].x = -INFINITY;
            if (s == 3) d2[1].y = -INFINITY;
            if (s == 4) d2[2].x = -INFINITY;
            if (s == 5) d2[2].y = -INFINITY;
            if (s == 6) d2[3].x = -INFINITY;
            if (s == 7) d2[3].y = -INFINITY;
        }
    }
}

// ----------------------------- KNN ---------------------------------
// Stable top-4 smallest (d, idx) per centroid; self forced to -1.0.
// Block: 512 threads = 64 centroids x 8 partial scanners. Grid: B*64.
#define KPARTS 8
__global__ __launch_bounds__(512) void knn_kernel(const float* __restrict__ spatial,
                                                  const int* __restrict__ idxs,
                                                  int* __restrict__ nn)
{
#pragma clang fp contract(off)
    const int blk = blockIdx.x;
    const int b = blk >> 6;
    const int grp = blk & 63;
    const int tid = threadIdx.x;
    const int lc = tid >> 3;      // local centroid 0..63
    const int part = tid & 7;
    const float* sp = spatial + (size_t)b * NPTS * SD;
    const int cid = (grp << 6) + lc;
    const int ctr = idxs[b * MCENT + cid];
    const float c0 = sp[(size_t)ctr * SD + 0], c1 = sp[(size_t)ctr * SD + 1],
                c2 = sp[(size_t)ctr * SD + 2], c3 = sp[(size_t)ctr * SD + 3],
                c4 = sp[(size_t)ctr * SD + 4];

    float bd[4] = {INFINITY, INFINITY, INFINITY, INFINITY};
    int   bi[4] = {0x7fffffff, 0x7fffffff, 0x7fffffff, 0x7fffffff};

    __shared__ float tile[2048 * SD];            // 40 KB
    __shared__ float md[64][KPARTS][4];          // 8 KB
    __shared__ int   mi[64][KPARTS][4];          // 8 KB

    for (int t0 = 0; t0 < NPTS; t0 += 2048) {
        __syncthreads();
        for (int e = tid; e < 2048 * SD; e += 512) tile[e] = sp[(size_t)t0 * SD + e];
        __syncthreads();
        for (int p = part; p < 2048; p += KPARTS) {
            const int gp = t0 + p;
            float x0 = tile[p * SD + 0] - c0; float d = x0 * x0;
            float x1 = tile[p * SD + 1] - c1; d = d + x1 * x1;
            float x2 = tile[p * SD + 2] - c2; d = d + x2 * x2;
            float x3 = tile[p * SD + 3] - c3; d = d + x3 * x3;
            float x4 = tile[p * SD + 4] - c4; d = d + x4 * x4;
            if (gp == ctr) d = -1.0f;
            const bool lt0 = (d < bd[0]) || (d == bd[0] && gp < bi[0]);
            const bool lt1 = (d < bd[1]) || (d == bd[1] && gp < bi[1]);
            const bool lt2 = (d < bd[2]) || (d == bd[2] && gp < bi[2]);
            const bool lt3 = (d < bd[3]) || (d == bd[3] && gp < bi[3]);
            if (lt3) {
                bd[3] = lt2 ? bd[2] : d;  bi[3] = lt2 ? bi[2] : gp;
                if (lt2) {
                    bd[2] = lt1 ? bd[1] : d;  bi[2] = lt1 ? bi[1] : gp;
                    if (lt1) {
                        bd[1] = lt0 ? bd[0] : d;  bi[1] = lt0 ? bi[0] : gp;
                        if (lt0) { bd[0] = d; bi[0] = gp; }
                    }
                }
            }
        }
    }
#pragma unroll
    for (int s = 0; s < 4; ++s) { md[lc][part][s] = bd[s]; mi[lc][part][s] = bi[s]; }
    __syncthreads();
    if (part == 0) {
        int ptr[KPARTS] = {0, 0, 0, 0, 0, 0, 0, 0};
        int outi[4];
        for (int s = 0; s < 4; ++s) {
            float bestd = INFINITY; int besti = 0x7fffffff; int bl = 0;
            for (int l = 0; l < KPARTS; ++l) {
                const int pl = ptr[l];
                if (pl < 4) {
                    const float dv = md[lc][l][pl];
                    const int   iv = mi[lc][l][pl];
                    if (dv < bestd || (dv == bestd && iv < besti)) { bestd = dv; besti = iv; bl = l; }
                }
            }
            ptr[bl]++;
            outi[s] = besti;
        }
        int* o = nn + ((size_t)b * MCENT + cid) * 3;
        o[0] = outi[1]; o[1] = outi[2]; o[2] = outi[3];   // skip self
    }
}

// --------------------------- gather --------------------------------
// Builds A_sa [B*M*3, 69] = [nbr_feat | rel] and writes centroids to d_out.
__global__ __launch_bounds__(256) void gather_kernel(const float* __restrict__ x,
                                                     const float* __restrict__ spatial,
                                                     const int* __restrict__ idxs,
                                                     const int* __restrict__ nn,
                                                     float* __restrict__ Asa,
                                                     float* __restrict__ cent_out)
{
    const int r = blockIdx.x;           // 0..B*M-1
    const int b = r >> 12;
    const int tid = threadIdx.x;
    const float* sp = spatial + (size_t)b * NPTS * SD;
    const float* xb = x + (size_t)b * NPTS * FD;
    const int ctr = idxs[r];
    __shared__ int nnk[3];
    if (tid < 3) nnk[tid] = nn[(size_t)r * 3 + tid];
    __syncthreads();
    if (tid < 192) {
        const int k = tid >> 6, c = tid & 63;
        Asa[((size_t)r * 3 + k) * 69 + c] = xb[(size_t)nnk[k] * FD + c];
    } else if (tid < 207) {
        const int e = tid - 192; const int k = e / 5, c = e % 5;
        Asa[((size_t)r * 3 + k) * 69 + 64 + c] =
            sp[(size_t)nnk[k] * SD + c] - sp[(size_t)ctr * SD + c];
    } else if (tid < 212) {
        const int c = tid - 207;
        cent_out[(size_t)r * SD + c] = sp[(size_t)ctr * SD + c];
    }
}

// ---------------------------- GEMM ---------------------------------
// C[M,N] = A[M,K] @ B[K,N] + bias ; EPI: 0 none, 1 relu, 2 +extra
template<int EPI>
__global__ __launch_bounds__(256) void gemm_kernel(const float* __restrict__ A,
                                                   const float* __restrict__ Bw,
                                                   const float* __restrict__ bias,
                                                   const float* __restrict__ extra,
                                                   float* __restrict__ C,
                                                   int Mrows, int Kdim, int Ncols)
{
    __shared__ float As[16][64];
    __shared__ float Bs[16][64];
    const int tid = threadIdx.x;
    const int tx = tid & 15, ty = tid >> 4;
    const int m0 = blockIdx.y << 6, n0 = blockIdx.x << 6;
    float acc[4][4] = {};
    for (int k0 = 0; k0 < Kdim; k0 += 16) {
#pragma unroll
        for (int i = 0; i < 4; ++i) {
            const int e = tid + (i << 8);
            const int col = e & 63, row = e >> 6;
            const int gk = k0 + row;
            As[row][col] = (gk < Kdim) ? A[(size_t)(m0 + col) * Kdim + gk] : 0.f;
            Bs[row][col] = (gk < Kdim) ? Bw[(size_t)gk * Ncols + n0 + col] : 0.f;
        }
        __syncthreads();
#pragma unroll
        for (int kk = 0; kk < 16; ++kk) {
            const float4 ra = *(const float4*)(&As[kk][ty << 2]);
            const float4 rb = *(const float4*)(&Bs[kk][tx << 2]);
            const float av[4] = {ra.x, ra.y, ra.z, ra.w};
            const float bv[4] = {rb.x, rb.y, rb.z, rb.w};
#pragma unroll
            for (int ii = 0; ii < 4; ++ii)
#pragma unroll
                for (int jj = 0; jj < 4; ++jj)
                    acc[ii][jj] = fmaf(av[ii], bv[jj], acc[ii][jj]);
        }
        __syncthreads();
    }
#pragma unroll
    for (int ii = 0; ii < 4; ++ii) {
        const int gm = m0 + (ty << 2) + ii;
#pragma unroll
        for (int jj = 0; jj < 4; ++jj) {
            const int gn = n0 + (tx << 2) + jj;
            float v = acc[ii][jj] + bias[gn];
            if (EPI == 1) v = fmaxf(v, 0.f);
            if (EPI == 2) v += extra[(size_t)gm * Ncols + gn];
            C[(size_t)gm * Ncols + gn] = v;
        }
    }
}

// ------------------------- BN + max over k -------------------------
__global__ __launch_bounds__(256) void bnmax_kernel(const float* __restrict__ h,
                                                    const float* __restrict__ g,
                                                    const float* __restrict__ be,
                                                    const float* __restrict__ mu,
                                                    const float* __restrict__ var,
                                                    float* __restrict__ f)
{
    const int r = blockIdx.x;          // 0..B*M-1
    const int m = r & (MCENT - 1);
    const int c = threadIdx.x;
    const float inv = g[m] / sqrtf(var[m] + 1e-5f);
    const float shift = be[m] - mu[m] * inv;
    const size_t base = (size_t)r * 3 * AD + c;
    const float v0 = fmaxf(h[base] * inv + shift, 0.f);
    const float v1 = fmaxf(h[base + AD] * inv + shift, 0.f);
    const float v2 = fmaxf(h[base + 2 * AD] * inv + shift, 0.f);
    f[(size_t)r * AD + c] = fmaxf(v0, fmaxf(v1, v2));
}

// ------------------------- W_q - W_k precompute --------------------
__global__ void wdiff_kernel(const float* __restrict__ Wq, const float* __restrict__ bq,
                             const float* __restrict__ Wk, const float* __restrict__ bk,
                             float* __restrict__ Wqk, float* __restrict__ bqk)
{
    const int i = blockIdx.x * blockDim.x + threadIdx.x;
    if (i < AD * AD) Wqk[i] = Wq[i] - Wk[i];
    if (i < AD) bqk[i] = bq[i] - bk[i];
}

// --------------------------- softmax -------------------------------
__global__ __launch_bounds__(256) void softmax_kernel(float* __restrict__ s)
{
    const int r = blockIdx.x;
    const int c = threadIdx.x;
    const int lane = c & 63, w = c >> 6;
    float v = s[(size_t)r * AD + c];
    float mx = v;
#pragma unroll
    for (int off = 1; off < 64; off <<= 1) mx = fmaxf(mx, __shfl_xor(mx, off, 64));
    __shared__ float sm[4];
    __shared__ float ss[4];
    if (lane == 0) sm[w] = mx;
    __syncthreads();
    mx = fmaxf(fmaxf(sm[0], sm[1]), fmaxf(sm[2], sm[3]));
    const float e = expf(v - mx);
    float sum = e;
#pragma unroll
    for (int off = 1; off < 64; off <<= 1) sum += __shfl_xor(sum, off, 64);
    if (lane == 0) ss[w] = sum;
    __syncthreads();
    sum = ss[0] + ss[1] + ss[2] + ss[3];
    s[(size_t)r * AD + c] = e / sum;
}

// --------------------------- w * v ---------------------------------
__global__ void mul_kernel(const float* __restrict__ w, float* __restrict__ v, int n)
{
    for (int i = blockIdx.x * blockDim.x + threadIdx.x; i < n; i += gridDim.x * blockDim.x)
        v[i] = w[i] * v[i];
}

// ---------------------------- launch -------------------------------
extern "C" void kernel_launch(void* const* d_in, const int* in_sizes, int n_in,
                              void* d_out, int out_size, void* d_ws, size_t ws_size,
                              hipStream_t stream)
{
    const float* x       = (const float*)d_in[0];
    const float* spatial = (const float*)d_in[1];
    const float* W_sa  = (const float*)d_in[2];
    const float* b_sa  = (const float*)d_in[3];
    const float* gamma = (const float*)d_in[4];
    const float* beta  = (const float*)d_in[5];
    const float* mean  = (const float*)d_in[6];
    const float* var   = (const float*)d_in[7];
    const float* W_in  = (const float*)d_in[8];
    const float* b_in  = (const float*)d_in[9];
    const float* W_q   = (const float*)d_in[10];
    const float* b_q   = (const float*)d_in[11];
    const float* W_k   = (const float*)d_in[12];
    const float* b_k   = (const float*)d_in[13];
    const float* W_v   = (const float*)d_in[14];
    const float* b_v   = (const float*)d_in[15];
    const float* W_w1  = (const float*)d_in[16];
    const float* b_w1  = (const float*)d_in[17];
    const float* W_w2  = (const float*)d_in[18];
    const float* b_w2  = (const float*)d_in[19];
    const float* W_out = (const float*)d_in[20];
    const float* b_out = (const float*)d_in[21];

    float* ws = (float*)d_ws;
    size_t o = 0;
    int* idxs = (int*)(ws + o); o += BATCH * MCENT;                 // 8192
    int* nn   = (int*)(ws + o); o += BATCH * MCENT * 3;             // 24576
    float* Wqk = ws + o; o += AD * AD;
    float* bqk = ws + o; o += AD;
    float* Asa = ws + o; o += (size_t)BATCH * MCENT * 3 * 69;       // 1695744
    float* h   = ws + o; o += (size_t)BATCH * MCENT * 3 * AD;       // 6291456
    float* f   = ws + o; o += (size_t)BATCH * MCENT * AD;           // 2097152
    float* u   = ws + o; o += (size_t)BATCH * MCENT * AD;           // 2097152
    // reuse h region after bnmax: t, qd, v ; reuse qd region for sgm
    float* t   = h;
    float* qd  = h + (size_t)BATCH * MCENT * AD;
    float* v   = h + (size_t)2 * BATCH * MCENT * AD;
    float* sgm = qd;

    float* outp = (float*)d_out;
    float* cent = outp + (size_t)BATCH * MCENT * AD;

    const int ROWS = BATCH * MCENT;          // 8192
    const int HROWS = ROWS * 3;              // 24576

    fps_kernel<<<BATCH, FPS_T, 0, stream>>>(spatial, idxs);
    knn_kernel<<<BATCH * 64, 512, 0, stream>>>(spatial, idxs, nn);
    gather_kernel<<<ROWS, 256, 0, stream>>>(x, spatial, idxs, nn, Asa, cent);
    wdiff_kernel<<<(AD * AD + 255) / 256, 256, 0, stream>>>(W_q, b_q, W_k, b_k, Wqk, bqk);

    gemm_kernel<0><<<dim3(AD / 64, HROWS / 64), 256, 0, stream>>>(Asa, W_sa, b_sa, nullptr, h, HROWS, 69, AD);
    bnmax_kernel<<<ROWS, 256, 0, stream>>>(h, gamma, beta, mean, var, f);
    gemm_kernel<0><<<dim3(AD / 64, ROWS / 64), 256, 0, stream>>>(f, W_in, b_in, nullptr, t, ROWS, AD, AD);
    gemm_kernel<0><<<dim3(AD / 64, ROWS / 64), 256, 0, stream>>>(t, Wqk, bqk, nullptr, qd, ROWS, AD, AD);
    gemm_kernel<0><<<dim3(AD / 64, ROWS / 64), 256, 0, stream>>>(t, W_v, b_v, nullptr, v, ROWS, AD, AD);
    gemm_kernel<1><<<dim3(AD / 64, ROWS / 64), 256, 0, stream>>>(qd, W_w1, b_w1, nullptr, u, ROWS, AD, AD);
    gemm_kernel<0><<<dim3(AD / 64, ROWS / 64), 256, 0, stream>>>(u, W_w2, b_w2, nullptr, sgm, ROWS, AD, AD);
    softmax_kernel<<<ROWS, 256, 0, stream>>>(sgm);
    mul_kernel<<<2048, 256, 0, stream>>>(sgm, v, ROWS * AD);
    gemm_kernel<2><<<dim3(AD / 64, ROWS / 64), 256, 0, stream>>>(v, W_out, b_out, f, outp, ROWS, AD, AD);
}

// Round 12
// 5314.503 us; speedup vs baseline: 1.0239x; 1.0239x over previous
//
#include <hip/hip_runtime.h>
#include <math.h>

#define NPTS 8192
#define BATCH 2
#define MCENT 4096
#define FD 64
#define SD 5
#define AD 256

typedef float f32x2 __attribute__((ext_vector_type(2)));
typedef float f32x4 __attribute__((ext_vector_type(4)));
typedef short short8 __attribute__((ext_vector_type(8)));

// ----------------------------- FPS ---------------------------------
// r9 configuration EXACTLY (best measured: 4641-4643us). r10's diet
// (packed minmax, multi-lane atomic, owner-branch mask) regressed +4%:
// fps is at an issue/latency equilibrium; the removed insts overlapped
// the serial tail. Do not re-apply without disasm evidence.
#define FPS_T 1024
#define FPS_PAIRS 4

template<int CTRL>
__device__ __forceinline__ float dpp_max_f(float x) {
    const int o = __builtin_amdgcn_update_dpp(
        (int)0xff800000, __float_as_int(x), CTRL, 0xf, 0xf, false); // old = -inf
    return fmaxf(x, __int_as_float(o));
}
template<int CTRL>
__device__ __forceinline__ int dpp_min_i(int x) {
    const int o = __builtin_amdgcn_update_dpp(
        0x7fffffff, x, CTRL, 0xf, 0xf, false);                      // old = +max
    return min(x, o);
}

__global__ __launch_bounds__(FPS_T) __attribute__((amdgpu_waves_per_eu(4, 4)))
void fps_kernel(const float* __restrict__ spatial, int* __restrict__ idxs)
{
#pragma clang fp contract(fast)
    const int b = blockIdx.x;
    const int tid = threadIdx.x;
    const float* sp = spatial + (size_t)b * NPTS * SD;
    int* out = idxs + (size_t)b * MCENT;

    __shared__ float cs0[NPTS];              // pivot-broadcast copies (32KB x4)
    __shared__ float cs1[NPTS];
    __shared__ float cs2[NPTS];
    __shared__ float cs3[NPTS];
    __shared__ unsigned long long gk[2];     // parity-double-buffered winner key

    for (int e = tid; e < NPTS; e += FPS_T) {
        cs0[e] = sp[(size_t)e * SD + 0];
        cs1[e] = sp[(size_t)e * SD + 1];
        cs2[e] = sp[(size_t)e * SD + 2];
        cs3[e] = sp[(size_t)e * SD + 3];
    }
    if (tid == 0) { gk[0] = 0ull; gk[1] = 0ull; }

    // per-thread coords fully in registers
    f32x2 P0[FPS_PAIRS], P1[FPS_PAIRS], P2[FPS_PAIRS], P3[FPS_PAIRS], P4[FPS_PAIRS];
    f32x2 d2[FPS_PAIRS];
#pragma unroll
    for (int q = 0; q < FPS_PAIRS; ++q) {
        const int p0 = tid + ((2 * q) << 10);
        const int p1 = p0 + 1024;
        P0[q].x = sp[(size_t)p0 * SD + 0]; P0[q].y = sp[(size_t)p1 * SD + 0];
        P1[q].x = sp[(size_t)p0 * SD + 1]; P1[q].y = sp[(size_t)p1 * SD + 1];
        P2[q].x = sp[(size_t)p0 * SD + 2]; P2[q].y = sp[(size_t)p1 * SD + 2];
        P3[q].x = sp[(size_t)p0 * SD + 3]; P3[q].y = sp[(size_t)p1 * SD + 3];
        P4[q].x = sp[(size_t)p0 * SD + 4]; P4[q].y = sp[(size_t)p1 * SD + 4];
        d2[q].x = INFINITY; d2[q].y = INFINITY;
    }
    // pin coords (52 VGPR — fits budget, no spill/remat)
#pragma unroll
    for (int q = 0; q < FPS_PAIRS; ++q) {
        asm volatile("" : "+v"(P0[q]));
        asm volatile("" : "+v"(P1[q]));
        asm volatile("" : "+v"(P2[q]));
        asm volatile("" : "+v"(P3[q]));
        asm volatile("" : "+v"(P4[q]));
    }

    if (tid == 0) { d2[0].x = -INFINITY; out[0] = 0; }   // point 0 pre-selected

    float l0 = sp[0], l1 = sp[1], l2 = sp[2], l3 = sp[3], l4 = sp[4];
    const int lane = tid & 63;
    __syncthreads();

    for (int i = 1; i < MCENT; ++i) {
        const int par = i & 1;
        const f32x2 L0 = {l0, l0}, L1 = {l1, l1}, L2 = {l2, l2},
                    L3 = {l3, l3}, L4 = {l4, l4};

        // pass A: dims 0..3 (l4's load latency hides under this)
        f32x2 s03[FPS_PAIRS];
#pragma unroll
        for (int q = 0; q < FPS_PAIRS; ++q) {
            f32x2 dx = P0[q] - L0; f32x2 s = dx * dx;
            f32x2 dy = P1[q] - L1; s = s + dy * dy;
            f32x2 dz = P2[q] - L2; s = s + dz * dz;
            f32x2 dw = P3[q] - L3; s = s + dw * dw;
            s03[q] = s;
        }
        // pass B: + dim4, min-update, running max
        float bv = -INFINITY;
#pragma unroll
        for (int q = 0; q < FPS_PAIRS; ++q) {
            f32x2 du = P4[q] - L4;
            f32x2 s = s03[q] + du * du;
            f32x2 nd;
            nd.x = fminf(d2[q].x, s.x);    // -inf mask absorbing
            nd.y = fminf(d2[q].y, s.y);
            d2[q] = nd;
            bv = fmaxf(bv, fmaxf(nd.x, nd.y));
        }
        // per-thread lowest index achieving bv (descending scan)
        int bi = 0x7fffffff;
#pragma unroll
        for (int q = FPS_PAIRS - 1; q >= 0; --q) {
            const int p0 = tid + ((2 * q) << 10);
            if (d2[q].y == bv) bi = p0 + 1024;
            if (d2[q].x == bv) bi = p0;
        }

        // wave-level value max via DPP (result lands in lane 63)
        float m = bv;
        m = dpp_max_f<0x111>(m);   // row_shr:1
        m = dpp_max_f<0x112>(m);   // row_shr:2
        m = dpp_max_f<0x114>(m);   // row_shr:4
        m = dpp_max_f<0x118>(m);   // row_shr:8
        m = dpp_max_f<0x142>(m);   // row_bcast:15
        m = dpp_max_f<0x143>(m);   // row_bcast:31
        const float wm = __int_as_float(
            __builtin_amdgcn_readlane(__float_as_int(m), 63));
        // lowest index among lanes holding wm
        int cand = (bv == wm) ? bi : 0x7fffffff;
        cand = dpp_min_i<0x111>(cand);
        cand = dpp_min_i<0x112>(cand);
        cand = dpp_min_i<0x114>(cand);
        cand = dpp_min_i<0x118>(cand);
        cand = dpp_min_i<0x142>(cand);
        cand = dpp_min_i<0x143>(cand);
        const int wi = __builtin_amdgcn_readlane(cand, 63);

        // cross-wave: one u64 LDS atomicMax per wave leader
        if (lane == 0) {
            unsigned long long key =
                (((unsigned long long)(unsigned)__float_as_int(wm)) << 32)
                | (unsigned)(~wi);
            key ^= 0x8000000000000000ull;        // signed order -> unsigned max
            atomicMax(&gk[par], key);
        }
        if (tid == 0) gk[par ^ 1] = 0ull;        // reset other slot pre-barrier
        __syncthreads();

        const unsigned long long k = gk[par];
        const int gidx = ~((int)(unsigned)k);    // low word = ~idx
        // pivot loads first: global c4 (L2, hidden under pass A),
        // then LDS c0..c3 broadcast
        const int su = __builtin_amdgcn_readfirstlane(gidx);
        l4 = sp[(size_t)su * SD + 4];
        l0 = cs0[su]; l1 = cs1[su]; l2 = cs2[su]; l3 = cs3[su];
        if (tid == 0) out[i] = gidx;
        // mask the selected point (static indices only)
        const int dlt = gidx - tid;
#pragma unroll
        for (int q = 0; q < FPS_PAIRS; ++q) {
            if (dlt == ((2 * q) << 10))     d2[q].x = -INFINITY;
            if (dlt == ((2 * q + 1) << 10)) d2[q].y = -INFINITY;
        }
    }
}

// ----------------------------- KNN ---------------------------------
// Stable top-4 smallest (d, idx) per centroid; self forced to -1.0.
// Block: 512 threads = 64 centroids x 8 partial scanners. Grid: B*64.
#define KPARTS 8
__global__ __launch_bounds__(512) void knn_kernel(const float* __restrict__ spatial,
                                                  const int* __restrict__ idxs,
                                                  int* __restrict__ nn)
{
#pragma clang fp contract(off)
    const int blk = blockIdx.x;
    const int b = blk >> 6;
    const int grp = blk & 63;
    const int tid = threadIdx.x;
    const int lc = tid >> 3;      // local centroid 0..63
    const int part = tid & 7;
    const float* sp = spatial + (size_t)b * NPTS * SD;
    const int cid = (grp << 6) + lc;
    const int ctr = idxs[b * MCENT + cid];
    const float c0 = sp[(size_t)ctr * SD + 0], c1 = sp[(size_t)ctr * SD + 1],
                c2 = sp[(size_t)ctr * SD + 2], c3 = sp[(size_t)ctr * SD + 3],
                c4 = sp[(size_t)ctr * SD + 4];

    float bd[4] = {INFINITY, INFINITY, INFINITY, INFINITY};
    int   bi[4] = {0x7fffffff, 0x7fffffff, 0x7fffffff, 0x7fffffff};

    __shared__ float tile[2048 * SD];            // 40 KB
    __shared__ float md[64][KPARTS][4];          // 8 KB
    __shared__ int   mi[64][KPARTS][4];          // 8 KB

    for (int t0 = 0; t0 < NPTS; t0 += 2048) {
        __syncthreads();
        for (int e = tid; e < 2048 * SD; e += 512) tile[e] = sp[(size_t)t0 * SD + e];
        __syncthreads();
        for (int p = part; p < 2048; p += KPARTS) {
            const int gp = t0 + p;
            float x0 = tile[p * SD + 0] - c0; float d = x0 * x0;
            float x1 = tile[p * SD + 1] - c1; d = d + x1 * x1;
            float x2 = tile[p * SD + 2] - c2; d = d + x2 * x2;
            float x3 = tile[p * SD + 3] - c3; d = d + x3 * x3;
            float x4 = tile[p * SD + 4] - c4; d = d + x4 * x4;
            if (gp == ctr) d = -1.0f;
            const bool lt0 = (d < bd[0]) || (d == bd[0] && gp < bi[0]);
            const bool lt1 = (d < bd[1]) || (d == bd[1] && gp < bi[1]);
            const bool lt2 = (d < bd[2]) || (d == bd[2] && gp < bi[2]);
            const bool lt3 = (d < bd[3]) || (d == bd[3] && gp < bi[3]);
            if (lt3) {
                bd[3] = lt2 ? bd[2] : d;  bi[3] = lt2 ? bi[2] : gp;
                if (lt2) {
                    bd[2] = lt1 ? bd[1] : d;  bi[2] = lt1 ? bi[1] : gp;
                    if (lt1) {
                        bd[1] = lt0 ? bd[0] : d;  bi[1] = lt0 ? bi[0] : gp;
                        if (lt0) { bd[0] = d; bi[0] = gp; }
                    }
                }
            }
        }
    }
#pragma unroll
    for (int s = 0; s < 4; ++s) { md[lc][part][s] = bd[s]; mi[lc][part][s] = bi[s]; }
    __syncthreads();
    if (part == 0) {
        int ptr[KPARTS] = {0, 0, 0, 0, 0, 0, 0, 0};
        int outi[4];
        for (int s = 0; s < 4; ++s) {
            float bestd = INFINITY; int besti = 0x7fffffff; int bl = 0;
            for (int l = 0; l < KPARTS; ++l) {
                const int pl = ptr[l];
                if (pl < 4) {
                    const float dv = md[lc][l][pl];
                    const int   iv = mi[lc][l][pl];
                    if (dv < bestd || (dv == bestd && iv < besti)) { bestd = dv; besti = iv; bl = l; }
                }
            }
            ptr[bl]++;
            outi[s] = besti;
        }
        int* o = nn + ((size_t)b * MCENT + cid) * 3;
        o[0] = outi[1]; o[1] = outi[2]; o[2] = outi[3];   // skip self
    }
}

// --------------------------- gather --------------------------------
// Builds A_sa [B*M*3, 69] = [nbr_feat | rel] and writes centroids to d_out.
__global__ __launch_bounds__(256) void gather_kernel(const float* __restrict__ x,
                                                     const float* __restrict__ spatial,
                                                     const int* __restrict__ idxs,
                                                     const int* __restrict__ nn,
                                                     float* __restrict__ Asa,
                                                     float* __restrict__ cent_out)
{
    const int r = blockIdx.x;           // 0..B*M-1
    const int b = r >> 12;
    const int tid = threadIdx.x;
    const float* sp = spatial + (size_t)b * NPTS * SD;
    const float* xb = x + (size_t)b * NPTS * FD;
    const int ctr = idxs[r];
    __shared__ int nnk[3];
    if (tid < 3) nnk[tid] = nn[(size_t)r * 3 + tid];
    __syncthreads();
    if (tid < 192) {
        const int k = tid >> 6, c = tid & 63;
        Asa[((size_t)r * 3 + k) * 69 + c] = xb[(size_t)nnk[k] * FD + c];
    } else if (tid < 207) {
        const int e = tid - 192; const int k = e / 5, c = e % 5;
        Asa[((size_t)r * 3 + k) * 69 + 64 + c] =
            sp[(size_t)nnk[k] * SD + c] - sp[(size_t)ctr * SD + c];
    } else if (tid < 212) {
        const int c = tid - 207;
        cent_out[(size_t)r * SD + c] = sp[(size_t)ctr * SD + c];
    }
}

// ---------------------- bf16 MFMA GEMM -----------------------------
// C[M,N] = A[M,K] @ B[K,N] + bias ; EPI: 0 none, 1 relu, 2 +extra.
// Inputs converted f32->bf16 (RNE) at LDS staging; f32 accumulation via
// v_mfma_f32_16x16x32_bf16; f32 epilogue. 64x64 tile, 4 waves (2x2 of
// 32x32), 2x2 16x16 frags per wave. LDS rows padded to 40 bf16 (80B):
// 16B-aligned ds_read_b128 + spread bank starts.
// Fragment maps (AMD layout, m89-verified D): A: row=lane&15,
// k=(lane>>4)*8+j ; B(col-major staged Bs[n][k]): n=lane&15, same k ;
// D: col=lane&15, row=(lane>>4)*4+j.
__device__ __forceinline__ unsigned short f2bf(float f) {
    const unsigned u = __float_as_uint(f);
    const unsigned r = ((u >> 16) & 1u) + 0x7fffu;   // RNE
    return (unsigned short)((u + r) >> 16);
}

template<int EPI>
__global__ __launch_bounds__(256) void gemm_kernel(const float* __restrict__ A,
                                                   const float* __restrict__ Bw,
                                                   const float* __restrict__ bias,
                                                   const float* __restrict__ extra,
                                                   float* __restrict__ C,
                                                   int Mrows, int Kdim, int Ncols)
{
    __shared__ unsigned short As[64][40];   // [m][k]
    __shared__ unsigned short Bs[64][40];   // [n][k]  (B staged transposed)
    const int tid = threadIdx.x;
    const int m0 = blockIdx.y << 6, n0 = blockIdx.x << 6;
    const int w = tid >> 6, l = tid & 63;
    const int wm0 = (w >> 1) << 5, wn0 = (w & 1) << 5;
    const int fr = l & 15;            // frag row (A) / col (B/D)
    const int fk = l >> 4;            // k-group 0..3

    f32x4 acc[2][2] = {};

    const int arow = tid >> 2, akc = (tid & 3) << 3;   // A: 4 thr/row, 8 k each
    const int bn = tid & 63, bkg = (tid >> 6) << 3;    // B: 64 n, 4 thr/n, 8 k

    for (int k0 = 0; k0 < Kdim; k0 += 32) {
        __syncthreads();
        // stage A tile 64x32 (coalesced: threads 0-3 cover one 128B row-span)
#pragma unroll
        for (int j = 0; j < 8; ++j) {
            const int gk = k0 + akc + j;
            const float vv = (gk < Kdim) ? A[(size_t)(m0 + arow) * Kdim + gk] : 0.f;
            As[arow][akc + j] = f2bf(vv);
        }
        // stage B tile 32x64 transposed (lanes read consecutive n: coalesced)
#pragma unroll
        for (int j = 0; j < 8; ++j) {
            const int gk = k0 + bkg + j;
            const float vv = (gk < Kdim) ? Bw[(size_t)gk * Ncols + n0 + bn] : 0.f;
            Bs[bn][bkg + j] = f2bf(vv);
        }
        __syncthreads();
        const short8 a0 = *(const short8*)&As[wm0 + fr][fk << 3];
        const short8 a1 = *(const short8*)&As[wm0 + 16 + fr][fk << 3];
        const short8 b0 = *(const short8*)&Bs[wn0 + fr][fk << 3];
        const short8 b1 = *(const short8*)&Bs[wn0 + 16 + fr][fk << 3];
        acc[0][0] = __builtin_amdgcn_mfma_f32_16x16x32_bf16(a0, b0, acc[0][0], 0, 0, 0);
        acc[0][1] = __builtin_amdgcn_mfma_f32_16x16x32_bf16(a0, b1, acc[0][1], 0, 0, 0);
        acc[1][0] = __builtin_amdgcn_mfma_f32_16x16x32_bf16(a1, b0, acc[1][0], 0, 0, 0);
        acc[1][1] = __builtin_amdgcn_mfma_f32_16x16x32_bf16(a1, b1, acc[1][1], 0, 0, 0);
    }
#pragma unroll
    for (int r = 0; r < 2; ++r)
#pragma unroll
    for (int c = 0; c < 2; ++c)
#pragma unroll
    for (int j = 0; j < 4; ++j) {
        const int gm = m0 + wm0 + (r << 4) + (fk << 2) + j;
        const int gn = n0 + wn0 + (c << 4) + fr;
        float vv = acc[r][c][j] + bias[gn];
        if (EPI == 1) vv = fmaxf(vv, 0.f);
        if (EPI == 2) vv += extra[(size_t)gm * Ncols + gn];
        C[(size_t)gm * Ncols + gn] = vv;
    }
}

// ------------------------- BN + max over k -------------------------
__global__ __launch_bounds__(256) void bnmax_kernel(const float* __restrict__ h,
                                                    const float* __restrict__ g,
                                                    const float* __restrict__ be,
                                                    const float* __restrict__ mu,
                                                    const float* __restrict__ var,
                                                    float* __restrict__ f)
{
    const int r = blockIdx.x;          // 0..B*M-1
    const int m = r & (MCENT - 1);
    const int c = threadIdx.x;
    const float inv = g[m] / sqrtf(var[m] + 1e-5f);
    const float shift = be[m] - mu[m] * inv;
    const size_t base = (size_t)r * 3 * AD + c;
    const float v0 = fmaxf(h[base] * inv + shift, 0.f);
    const float v1 = fmaxf(h[base + AD] * inv + shift, 0.f);
    const float v2 = fmaxf(h[base + 2 * AD] * inv + shift, 0.f);
    f[(size_t)r * AD + c] = fmaxf(v0, fmaxf(v1, v2));
}

// ------------------------- W_q - W_k precompute --------------------
__global__ void wdiff_kernel(const float* __restrict__ Wq, const float* __restrict__ bq,
                             const float* __restrict__ Wk, const float* __restrict__ bk,
                             float* __restrict__ Wqk, float* __restrict__ bqk)
{
    const int i = blockIdx.x * blockDim.x + threadIdx.x;
    if (i < AD * AD) Wqk[i] = Wq[i] - Wk[i];
    if (i < AD) bqk[i] = bq[i] - bk[i];
}

// ------------------- softmax fused with w*v ------------------------
__global__ __launch_bounds__(256) void softmax_mul_kernel(const float* __restrict__ s,
                                                          float* __restrict__ v)
{
    const int r = blockIdx.x;
    const int c = threadIdx.x;
    const int lane = c & 63, w = c >> 6;
    const size_t idx = (size_t)r * AD + c;
    const float x = s[idx];
    float mx = x;
#pragma unroll
    for (int off = 1; off < 64; off <<= 1) mx = fmaxf(mx, __shfl_xor(mx, off, 64));
    __shared__ float sm[4];
    __shared__ float ss[4];
    if (lane == 0) sm[w] = mx;
    __syncthreads();
    mx = fmaxf(fmaxf(sm[0], sm[1]), fmaxf(sm[2], sm[3]));
    const float e = expf(x - mx);
    float sum = e;
#pragma unroll
    for (int off = 1; off < 64; off <<= 1) sum += __shfl_xor(sum, off, 64);
    if (lane == 0) ss[w] = sum;
    __syncthreads();
    sum = ss[0] + ss[1] + ss[2] + ss[3];
    v[idx] = (e / sum) * v[idx];
}

// ---------------------------- launch -------------------------------
extern "C" void kernel_launch(void* const* d_in, const int* in_sizes, int n_in,
                              void* d_out, int out_size, void* d_ws, size_t ws_size,
                              hipStream_t stream)
{
    const float* x       = (const float*)d_in[0];
    const float* spatial = (const float*)d_in[1];
    const float* W_sa  = (const float*)d_in[2];
    const float* b_sa  = (const float*)d_in[3];
    const float* gamma = (const float*)d_in[4];
    const float* beta  = (const float*)d_in[5];
    const float* mean  = (const float*)d_in[6];
    const float* var   = (const float*)d_in[7];
    const float* W_in  = (const float*)d_in[8];
    const float* b_in  = (const float*)d_in[9];
    const float* W_q   = (const float*)d_in[10];
    const float* b_q   = (const float*)d_in[11];
    const float* W_k   = (const float*)d_in[12];
    const float* b_k   = (const float*)d_in[13];
    const float* W_v   = (const float*)d_in[14];
    const float* b_v   = (const float*)d_in[15];
    const float* W_w1  = (const float*)d_in[16];
    const float* b_w1  = (const float*)d_in[17];
    const float* W_w2  = (const float*)d_in[18];
    const float* b_w2  = (const float*)d_in[19];
    const float* W_out = (const float*)d_in[20];
    const float* b_out = (const float*)d_in[21];

    float* ws = (float*)d_ws;
    size_t o = 0;
    int* idxs = (int*)(ws + o); o += BATCH * MCENT;                 // 8192
    int* nn   = (int*)(ws + o); o += BATCH * MCENT * 3;             // 24576
    float* Wqk = ws + o; o += AD * AD;
    float* bqk = ws + o; o += AD;
    float* Asa = ws + o; o += (size_t)BATCH * MCENT * 3 * 69;       // 1695744
    float* h   = ws + o; o += (size_t)BATCH * MCENT * 3 * AD;       // 6291456
    float* f   = ws + o; o += (size_t)BATCH * MCENT * AD;           // 2097152
    float* u   = ws + o; o += (size_t)BATCH * MCENT * AD;           // 2097152
    // reuse h region after bnmax: t, qd, v ; reuse qd region for sgm
    float* t   = h;
    float* qd  = h + (size_t)BATCH * MCENT * AD;
    float* v   = h + (size_t)2 * BATCH * MCENT * AD;
    float* sgm = qd;

    float* outp = (float*)d_out;
    float* cent = outp + (size_t)BATCH * MCENT * AD;

    const int ROWS = BATCH * MCENT;          // 8192
    const int HROWS = ROWS * 3;              // 24576

    fps_kernel<<<BATCH, FPS_T, 0, stream>>>(spatial, idxs);
    knn_kernel<<<BATCH * 64, 512, 0, stream>>>(spatial, idxs, nn);
    gather_kernel<<<ROWS, 256, 0, stream>>>(x, spatial, idxs, nn, Asa, cent);
    wdiff_kernel<<<(AD * AD + 255) / 256, 256, 0, stream>>>(W_q, b_q, W_k, b_k, Wqk, bqk);

    gemm_kernel<0><<<dim3(AD / 64, HROWS / 64), 256, 0, stream>>>(Asa, W_sa, b_sa, nullptr, h, HROWS, 69, AD);
    bnmax_kernel<<<ROWS, 256, 0, stream>>>(h, gamma, beta, mean, var, f);
    gemm_kernel<0><<<dim3(AD / 64, ROWS / 64), 256, 0, stream>>>(f, W_in, b_in, nullptr, t, ROWS, AD, AD);
    gemm_kernel<0><<<dim3(AD / 64, ROWS / 64), 256, 0, stream>>>(t, Wqk, bqk, nullptr, qd, ROWS, AD, AD);
    gemm_kernel<0><<<dim3(AD / 64, ROWS / 64), 256, 0, stream>>>(t, W_v, b_v, nullptr, v, ROWS, AD, AD);
    gemm_kernel<1><<<dim3(AD / 64, ROWS / 64), 256, 0, stream>>>(qd, W_w1, b_w1, nullptr, u, ROWS, AD, AD);
    gemm_kernel<0><<<dim3(AD / 64, ROWS / 64), 256, 0, stream>>>(u, W_w2, b_w2, nullptr, sgm, ROWS, AD, AD);
    softmax_mul_kernel<<<ROWS, 256, 0, stream>>>(sgm, v);
    gemm_kernel<2><<<dim3(AD / 64, ROWS / 64), 256, 0, stream>>>(v, W_out, b_out, f, outp, ROWS, AD, AD);
}